// Round 2
// 179.820 us; speedup vs baseline: 1.0205x; 1.0205x over previous
//
#include <hip/hip_runtime.h>

// Banded stereo cost volume, all 3 scales fused into ONE launch.
// cost[j,h,x] = sum_c L[c,h,x] * R[c,h,x-j], 0 if x<j. C=32.
//
// Round-5 retile: previous kernel was LDS-read-pipe bound (2.54M ds wave
// insts x ~12cy ~= 50us of 68us; HBM only 32%, VALU ~25%). Per-thread tile
// goes 8j x (4+4)x (8 b128 / 64 FMA = 2 B/FMA) -> 24j x 4x contiguous
// (1 L + 7 R aligned b128 / 96 FMA = 1.33 B/FMA). One aligned R register
// window rw[28] = Rs[rbase .. rbase+27] serves all 24 j via static indexing;
// rbase = 4tx - 24ty + 168 is 4-aligned by construction -> no swizzle, and
// the two wave halves read two contiguous 512B blocks (2-way aliasing = free).
// Block: 256 thr = 32 tx * 8 ty; tile TX=128 x, TJ=192 = all of D (no by
// split). D in {192,96,48} are multiples of JT=24 -> ty rows fully on/off.
// Stores keep the full-line property from rounds 2/4: per inst, 32 lanes x
// 16B stride-16 = 512B contiguous per j-row (avoids the 8.6x HBM write
// amplification seen with half-line strided stores).
//
// (Round-6 resubmit: round-5 bench died with "container failed twice" —
// infra error, no kernel diagnostics. Source re-audited for OOB/hangs; none.)

#define TX 128
#define TJ 192
#define JT 24
#define NCS 16   // channels per stage
#define NSTG 2
#define LSW 128  // Ls row stride (floats)
#define RSW 320  // Rs row stride (floats) = TX + TJ, staged [x0-192, x0+127]

#define NBLK_TOTAL 1344

typedef float vf4 __attribute__((ext_vector_type(4)));

__global__ __launch_bounds__(256, 2)
void cost_volume_fused(const float* __restrict__ L0, const float* __restrict__ R0,
                       const float* __restrict__ L1, const float* __restrict__ R1,
                       const float* __restrict__ L2, const float* __restrict__ R2,
                       float* __restrict__ out)
{
    __shared__ float Ls[NCS * LSW];   // 8 KB
    __shared__ float Rs[NCS * RSW];   // 20 KB

    const int id = blockIdx.x;
    const float* L; const float* R; float* o;
    int H, W, D, bx, h;
    if (id < 1024) {            // scale 0: H=256 W=512 D=192
        L = L0; R = R0; o = out;
        H = 256; W = 512; D = 192;
        bx = id & 3; h = id >> 2;
    } else if (id < 1280) {     // scale 1: H=128 W=256 D=96
        int r = id - 1024;
        L = L1; R = R1; o = out + (size_t)192 * 256 * 512;
        H = 128; W = 256; D = 96;
        bx = r & 1; h = r >> 1;
    } else {                    // scale 2: H=64 W=128 D=48
        int r = id - 1280;
        L = L2; R = R2; o = out + (size_t)192 * 256 * 512 + (size_t)96 * 128 * 256;
        H = 64; W = 128; D = 48;
        bx = 0; h = r;
    }

    const int x0 = bx * TX;
    const int t  = threadIdx.x;
    const int tx = t & 31;            // 0..31 -> x run = x0 + 4*tx
    const int ty = t >> 5;            // 0..7  -> j rows [24*ty, 24*ty+23]
    const int jbase = ty * JT;

    const size_t HW = (size_t)H * W;
    const float* Lb = L + (size_t)h * W;
    const float* Rb = R + (size_t)h * W;

    const bool active = (jbase < D);                          // rows exist
    const bool live   = active && (x0 + 4 * tx + 3 >= jbase); // not fully left of band

    float acc[JT][4];
    #pragma unroll
    for (int jj = 0; jj < JT; ++jj) {
        acc[jj][0] = 0.f; acc[jj][1] = 0.f; acc[jj][2] = 0.f; acc[jj][3] = 0.f;
    }

    // R window start (float idx into Rs row); needed idx = rbase + 24 + i - jj,
    // i in 0..3, jj in 0..23 -> rbase+1 .. rbase+27. rbase in [0, 292],
    // max read 292+27 = 319 < RSW. 4-aligned by construction.
    const int rbase = 4 * tx - JT * ty + (TJ - 24);

    #pragma unroll
    for (int s = 0; s < NSTG; ++s) {
        const int c0 = s * NCS;
        // ---- stage 16 channels into LDS ----
        // L: 512 float4, 2 iters of 256 threads (always in-bounds: x0+128 <= W)
        #pragma unroll
        for (int k = 0; k < 2; ++k) {
            int f = t + k * 256;
            int c = f >> 5, q = f & 31;
            vf4 v = *(const vf4*)(Lb + (size_t)(c0 + c) * HW + x0 + 4 * q);
            *(vf4*)&Ls[c * LSW + 4 * q] = v;
        }
        // R: 1280 float4 (80 f4/channel covering g in [x0-192, x0+127])
        #pragma unroll
        for (int k = 0; k < 5; ++k) {
            int f = t + k * 256;
            int c = f / 80;
            int q = f - 80 * c;
            int g = x0 - TJ + 4 * q;
            vf4 v = (vf4)(0.f);
            if (g >= 0 && g < W)    // g, W multiples of 4 -> whole float4 in bounds
                v = *(const vf4*)(Rb + (size_t)(c0 + c) * HW + g);
            *(vf4*)&Rs[c * RSW + 4 * q] = v;
        }
        __syncthreads();

        if (live) {
            #pragma unroll 1
            for (int c = 0; c < NCS; ++c) {
                const float* Lc = Ls + c * LSW;
                const float* Rc = Rs + c * RSW + rbase;
                float lv[4], rw[28];
                *(vf4*)&lv[0] = *(const vf4*)(Lc + 4 * tx);   // wave-halves broadcast
                #pragma unroll
                for (int k = 0; k < 7; ++k)
                    *(vf4*)&rw[4 * k] = *(const vf4*)(Rc + 4 * k);
                #pragma unroll
                for (int jj = 0; jj < JT; ++jj)
                    #pragma unroll
                    for (int i = 0; i < 4; ++i)
                        acc[jj][i] = fmaf(lv[i], rw[24 + i - jj], acc[jj][i]);
            }
        }
        if (s + 1 < NSTG) __syncthreads();   // protect LDS before next stage's writes
    }

    if (active) {
        // D in {192,96,48} is a multiple of JT, so all JT rows of an active
        // thread are in-range (jbase+23 <= D-1).
        #pragma unroll
        for (int jj = 0; jj < JT; ++jj) {
            int j = jbase + jj;
            float* p = o + ((size_t)j * H + h) * W + x0 + 4 * tx;
            vf4 v = {acc[jj][0], acc[jj][1], acc[jj][2], acc[jj][3]};
            __builtin_nontemporal_store(v, (vf4*)p);
        }
    }
}

extern "C" void kernel_launch(void* const* d_in, const int* in_sizes, int n_in,
                              void* d_out, int out_size, void* d_ws, size_t ws_size,
                              hipStream_t stream)
{
    const float* L0 = (const float*)d_in[0];
    const float* R0 = (const float*)d_in[1];
    const float* L1 = (const float*)d_in[2];
    const float* R1 = (const float*)d_in[3];
    const float* L2 = (const float*)d_in[4];
    const float* R2 = (const float*)d_in[5];
    float* out = (float*)d_out;

    cost_volume_fused<<<dim3(NBLK_TOTAL), dim3(256), 0, stream>>>(
        L0, R0, L1, R1, L2, R2, out);
}

// Round 4
// 173.073 us; speedup vs baseline: 1.0603x; 1.0390x over previous
//
#include <hip/hip_runtime.h>

// Banded stereo cost volume, all 3 scales fused into ONE launch.
// cost[j,h,x] = sum_c L[c,h,x] * R[c,h,x-j], 0 if x<j. C=32.
//
// Round-8: fix round-7's correctness failure (absmax 34.7). Cause:
// global_load_lds dest is wave-uniform-base + lane*16 (m104/m108/m173);
// the `if (q >= qpad)` pad guard masked the LEADING lanes of a wave, so
// the base came from the first active lane and every active lane wrote
// LDS shifted by +16*qpad -> R tile corrupted for x0<192 blocks.
// Fix: no partial-wave exec masks on gload_lds. Pad lanes CLAMP the global
// address (load valid garbage from g=0). Garbage lands only in Rs slots
// with logical g=x-j<0, which feed only outputs defined to be zero; those
// are zeroed in the epilogue with per-element selects (x>=j ? acc : 0).
// The only remaining gload guard (f<640) is wave-uniform (waves 2,3 off).
//
// Pipeline (round-7 structure, unchanged): double-buffered LDS, NCS=8 x 4
// stages, direct-to-LDS staging, stage(s+1) issued BEFORE compute(s), one
// __syncthreads per stage (its vmcnt(0) drain = completion guarantee; the
// m97-proven pattern). Compute core: thread = 24j x 4x, rw[28] register
// window, rbase 4-aligned, conflict-free b128, full-line 512B stores.

#define TX 128
#define TJ 192
#define JT 24
#define NCS 8    // channels per stage
#define NSTG 4
#define LSW 128  // Ls row stride (floats) = staged L width
#define RSW 320  // Rs row stride (floats) = staged R width [x0-192, x0+127]

#define NBLK_TOTAL 1344

typedef float vf4 __attribute__((ext_vector_type(4)));

__device__ __forceinline__ void gload_lds16(const float* g, float* l)
{
    __builtin_amdgcn_global_load_lds(
        (const __attribute__((address_space(1))) void*)g,
        (__attribute__((address_space(3))) void*)l,
        16, 0, 0);
}

__global__ __launch_bounds__(256, 3)
void cost_volume_fused(const float* __restrict__ L0, const float* __restrict__ R0,
                       const float* __restrict__ L1, const float* __restrict__ R1,
                       const float* __restrict__ L2, const float* __restrict__ R2,
                       float* __restrict__ out)
{
    __shared__ float Ls[2][NCS * LSW];   // 2 x 4 KB
    __shared__ float Rs[2][NCS * RSW];   // 2 x 10 KB

    const int id = blockIdx.x;
    const float* L; const float* R; float* o;
    int H, W, D, bx, h;
    if (id < 1024) {            // scale 0: H=256 W=512 D=192
        L = L0; R = R0; o = out;
        H = 256; W = 512; D = 192;
        bx = id & 3; h = id >> 2;
    } else if (id < 1280) {     // scale 1: H=128 W=256 D=96
        int r = id - 1024;
        L = L1; R = R1; o = out + (size_t)192 * 256 * 512;
        H = 128; W = 256; D = 96;
        bx = r & 1; h = r >> 1;
    } else {                    // scale 2: H=64 W=128 D=48
        int r = id - 1280;
        L = L2; R = R2; o = out + (size_t)192 * 256 * 512 + (size_t)96 * 128 * 256;
        H = 64; W = 128; D = 48;
        bx = 0; h = r;
    }

    const int x0 = bx * TX;
    const int t  = threadIdx.x;
    const int tx = t & 31;            // 0..31 -> x run = x0 + 4*tx
    const int ty = t >> 5;            // 0..7  -> j rows [24*ty, 24*ty+23]
    const int jbase = ty * JT;
    const int xg = x0 + 4 * tx;       // first x this thread owns

    const size_t HW = (size_t)H * W;
    const float* Lb = L + (size_t)h * W;
    const float* Rb = R + (size_t)h * W;

    const bool active = (jbase < D);                  // rows exist
    const bool live   = active && (xg + 3 >= jbase);  // not fully left of band

    float acc[JT][4];
    #pragma unroll
    for (int jj = 0; jj < JT; ++jj) {
        acc[jj][0] = 0.f; acc[jj][1] = 0.f; acc[jj][2] = 0.f; acc[jj][3] = 0.f;
    }

    // R window start (float idx into Rs row); needed idx = rbase + 24 + i - jj,
    // i in 0..3, jj in 0..23 -> rbase+1 .. rbase+27 <= 319 < RSW. 4-aligned.
    // Logical Rs float idx maps to g = x0 - 192 + idx, so read (i,jj) hits
    // g = x - j: slots with g<0 (clamped garbage) feed only x<j outputs.
    const int rbase = 4 * tx - JT * ty + (TJ - 24);

    // ---- async stage: 8 channels -> LDS buffer p, direct global->LDS ----
    // All gload_lds issued with full (or wave-uniform) exec; dest = 16*f linear.
    auto stage = [&](int c0, int p) {
        // L: 256 f4, one inst/thread; always in-bounds (x0+127 <= W-1).
        {
            int c = t >> 5, q = t & 31;
            gload_lds16(Lb + (size_t)(c0 + c) * HW + x0 + 4 * q, &Ls[p][4 * t]);
        }
        // R: 640 f4 (80/channel). g clamped to >=0 (pad -> valid garbage).
        #pragma unroll
        for (int k = 0; k < 3; ++k) {
            int f = t + k * 256;
            if (f < NCS * 80) {          // wave-uniform: waves 2,3 off at k=2
                int c = f / 80, q = f - 80 * c;
                int g = x0 - TJ + 4 * q;
                if (g < 0) g = 0;        // clamp: keeps 16B align, in-bounds
                gload_lds16(Rb + (size_t)(c0 + c) * HW + g, &Rs[p][4 * f]);
            }
        }
    };

    stage(0, 0);
    __syncthreads();   // vmcnt(0) drain -> stage 0 landed

    #pragma unroll
    for (int s = 0; s < NSTG; ++s) {
        if (s + 1 < NSTG) stage((s + 1) * NCS, (s + 1) & 1);  // fly under compute
        if (live) {
            const float* Lsb = Ls[s & 1];
            const float* Rsb = Rs[s & 1];
            #pragma unroll 1
            for (int c = 0; c < NCS; ++c) {
                const float* Lc = Lsb + c * LSW;
                const float* Rc = Rsb + c * RSW + rbase;
                float lv[4], rw[28];
                *(vf4*)&lv[0] = *(const vf4*)(Lc + 4 * tx);   // wave-halves broadcast
                #pragma unroll
                for (int k = 0; k < 7; ++k)
                    *(vf4*)&rw[4 * k] = *(const vf4*)(Rc + 4 * k);
                #pragma unroll
                for (int jj = 0; jj < JT; ++jj)
                    #pragma unroll
                    for (int i = 0; i < 4; ++i)
                        acc[jj][i] = fmaf(lv[i], rw[24 + i - jj], acc[jj][i]);
            }
        }
        // Barrier per stage: vmcnt(0)+lgkmcnt(0) drain guarantees stage(s+1)
        // landed; barrier guarantees no wave still reads buf being restaged.
        if (s + 1 < NSTG) __syncthreads();
    }

    if (active) {
        // D in {192,96,48} is a multiple of JT, so all JT rows in-range.
        // Band zeroing: element (jj,i) is valid iff x >= j, i.e.
        // xg + i >= jbase + jj. Garbage-fed elements are exactly x < j.
        #pragma unroll
        for (int jj = 0; jj < JT; ++jj) {
            int j = jbase + jj;
            float* p = o + ((size_t)j * H + h) * W + xg;
            vf4 v;
            #pragma unroll
            for (int i = 0; i < 4; ++i)
                v[i] = (xg + i >= j) ? acc[jj][i] : 0.f;
            __builtin_nontemporal_store(v, (vf4*)p);
        }
    }
}

extern "C" void kernel_launch(void* const* d_in, const int* in_sizes, int n_in,
                              void* d_out, int out_size, void* d_ws, size_t ws_size,
                              hipStream_t stream)
{
    const float* L0 = (const float*)d_in[0];
    const float* R0 = (const float*)d_in[1];
    const float* L1 = (const float*)d_in[2];
    const float* R1 = (const float*)d_in[3];
    const float* L2 = (const float*)d_in[4];
    const float* R2 = (const float*)d_in[5];
    float* out = (float*)d_out;

    cost_volume_fused<<<dim3(NBLK_TOTAL), dim3(256), 0, stream>>>(
        L0, R0, L1, R1, L2, R2, out);
}